// Round 12
// baseline (135.641 us; speedup 1.0000x reference)
//
#include <hip/hip_runtime.h>
#include <hip/hip_bf16.h>

#define B_    2
#define S_    2048
#define D_    1024
#define H_    16
#define KV_   4
#define QKB_  16
#define VB_   32
#define NTOK  (B_ * S_)   // 4096
#define L2E_  1.44269504088896f

typedef __attribute__((ext_vector_type(8))) short bshort8;
typedef __attribute__((ext_vector_type(4))) float f32x4;

__device__ __forceinline__ unsigned short bf16_rne(float x) {
    unsigned u = __float_as_uint(x);
    return (unsigned short)((u + 0x7FFFu + ((u >> 16) & 1u)) >> 16);
}
__device__ __forceinline__ unsigned bf16x2_rne(float lo, float hi) {
    return (unsigned)bf16_rne(lo) | ((unsigned)bf16_rne(hi) << 16);
}
__device__ __forceinline__ unsigned cvt_pk_bf16(float lo, float hi) {
    unsigned r;
    asm("v_cvt_pk_bf16_f32 %0, %1, %2" : "=v"(r) : "v"(lo), "v"(hi));
    return r;
}
__device__ __forceinline__ float sum2bf(unsigned u) {
    return __uint_as_float(u << 16) + __uint_as_float(u & 0xFFFF0000u);
}
__device__ __forceinline__ void stage16(const unsigned short* g, unsigned short* l) {
    __builtin_amdgcn_global_load_lds(
        (const __attribute__((address_space(1))) void*)g,
        (__attribute__((address_space(3))) void*)l, 16, 0, 0);
}

// ---------------- Prep: hs->bf16 (blocks 0..2047) + weight transpose (2048..2287) --
__global__ __launch_bounds__(256) void prep_kernel(
    const float* __restrict__ hs,
    const float* __restrict__ Wq, const float* __restrict__ Wk,
    const float* __restrict__ Wv, const float* __restrict__ Wo,
    unsigned short* __restrict__ hs_b,
    unsigned short* __restrict__ Wcat_t, unsigned short* __restrict__ Wot)
{
    __shared__ float T[64][65];
    const int t = threadIdx.x;
    if (blockIdx.x < 2048) {
        int i = blockIdx.x * 256 + t;
        const float4* s = (const float4*)hs;
        float4 a = s[2 * i], b = s[2 * i + 1];
        uint4 o;
        o.x = bf16x2_rne(a.x, a.y); o.y = bf16x2_rne(a.z, a.w);
        o.z = bf16x2_rne(b.x, b.y); o.w = bf16x2_rne(b.z, b.w);
        ((uint4*)hs_b)[i] = o;
        return;
    }
    const int bid = blockIdx.x - 2048;
    const float* src; unsigned short* dst; int K, N, tk, tn, drow0;
    if (bid < 64)       { src = Wq; dst = Wcat_t; K = 1024; N = 256;  int r = bid;       tk = r & 15; tn = r >> 4; drow0 = 0; }
    else if (bid < 80)  { src = Wk; dst = Wcat_t; K = 1024; N = 64;   int r = bid - 64;  tk = r;      tn = 0;      drow0 = 256; }
    else if (bid < 112) { src = Wv; dst = Wcat_t; K = 1024; N = 128;  int r = bid - 80;  tk = r & 15; tn = r >> 4; drow0 = 320; }
    else                { src = Wo; dst = Wot;    K = 512;  N = 1024; int r = bid - 112; tk = r & 7;  tn = r >> 3; drow0 = 0; }
    const int k0 = tk * 64, n0 = tn * 64;
    const int rr = t >> 4, cc = (t & 15) * 4;
    #pragma unroll
    for (int i = 0; i < 4; ++i) {
        float4 v = *(const float4*)(src + (k0 + rr + i * 16) * N + n0 + cc);
        T[rr + i * 16][cc + 0] = v.x; T[rr + i * 16][cc + 1] = v.y;
        T[rr + i * 16][cc + 2] = v.z; T[rr + i * 16][cc + 3] = v.w;
    }
    __syncthreads();
    const int nloc = t >> 2, kc = (t & 3) * 16;
    unsigned o[8];
    #pragma unroll
    for (int j = 0; j < 8; ++j)
        o[j] = bf16x2_rne(T[kc + 2 * j][nloc], T[kc + 2 * j + 1][nloc]);
    unsigned short* dp = dst + (drow0 + n0 + nloc) * K + k0 + kc;
    uint4 w0; w0.x = o[0]; w0.y = o[1]; w0.z = o[2]; w0.w = o[3];
    uint4 w1; w1.x = o[4]; w1.y = o[5]; w1.z = o[6]; w1.w = o[7];
    *(uint4*)(dp) = w0;
    *(uint4*)(dp + 8) = w1;
}

// ---------------- proj GEMM: 64x64 tile, BK=64, gl_lds + XOR-8 swizzle ---------
__global__ __launch_bounds__(256, 4) void proj_gemm(
    const unsigned short* __restrict__ Ab, const unsigned short* __restrict__ Btb,
    unsigned short* __restrict__ qg, unsigned short* __restrict__ pko,
    unsigned short* __restrict__ pvT)
{
    __shared__ unsigned short As[64 * 64];    // 8 KB
    __shared__ unsigned short Bs[64 * 64];    // 8 KB
    const int tid = threadIdx.x, l = tid & 63, w = tid >> 6;
    const int l15 = l & 15, quad = l >> 4;
    const int m0 = blockIdx.x * 64, n0 = blockIdx.y * 64;
    const int sr8 = l >> 3, sc8 = l & 7;
    f32x4 c[4];
    #pragma unroll
    for (int j = 0; j < 4; ++j) c[j] = (f32x4){0.f, 0.f, 0.f, 0.f};

    for (int k0 = 0; k0 < 1024; k0 += 64) {
        int R0 = w * 8, r0 = R0 + sr8;
        int R1 = 32 + w * 8, r1 = R1 + sr8;
        stage16(Ab  + (m0 + r0) * 1024 + k0 + (sc8 ^ (r0 & 7)) * 8, &As[R0 * 64]);
        stage16(Ab  + (m0 + r1) * 1024 + k0 + (sc8 ^ (r1 & 7)) * 8, &As[R1 * 64]);
        stage16(Btb + (n0 + r0) * 1024 + k0 + (sc8 ^ (r0 & 7)) * 8, &Bs[R0 * 64]);
        stage16(Btb + (n0 + r1) * 1024 + k0 + (sc8 ^ (r1 & 7)) * 8, &Bs[R1 * 64]);
        __syncthreads();
        #pragma unroll
        for (int kh = 0; kh < 2; ++kh) {
            const int arow = w * 16 + l15;
            bshort8 a = *(const bshort8*)&As[arow * 64 + (((kh * 4 + quad) ^ (arow & 7)) * 8)];
            #pragma unroll
            for (int bc = 0; bc < 4; ++bc) {
                const int brow = bc * 16 + l15;
                bshort8 b = *(const bshort8*)&Bs[brow * 64 + (((kh * 4 + quad) ^ (brow & 7)) * 8)];
                c[bc] = __builtin_amdgcn_mfma_f32_16x16x32_bf16(a, b, c[bc], 0, 0, 0);
            }
        }
        __syncthreads();
    }

    const int tok0 = m0 + w * 16 + quad * 4;
    #pragma unroll
    for (int bc = 0; bc < 4; ++bc) {
        f32x4 v = c[bc];
        const int n = n0 + bc * 16 + l15;
        float sg[4];
        #pragma unroll
        for (int r = 0; r < 4; ++r)
            sg[r] = 1.f / (1.f + exp2f(-v[r] * L2E_));
        if (n < 256) {
            const int hh = n >> 4, d = n & 15;
            #pragma unroll
            for (int r = 0; r < 4; ++r) {
                int tok = tok0 + r, bb = tok >> 11, ss = tok & 2047;
                qg[(((bb * 16 + hh) * 2048) + ss) * 16 + d] =
                    bf16_rne(L2E_ * (2.f * sg[r] - 1.f));
            }
        } else if (n < 320) {
            const int j = n - 256, kvv = j >> 4, d = j & 15;
            #pragma unroll
            for (int r = 0; r < 4; ++r) {
                int tok = tok0 + r, bb = tok >> 11, ss = tok & 2047;
                pko[(((bb * 4 + kvv) * 2048) + ss) * 16 + d] = bf16_rne(sg[r]);
            }
        } else {
            const int j = n - 320, kvv = j >> 5, d = j & 31;
            const int bb = tok0 >> 11, ss = tok0 & 2047;
            const int tl = ss >> 6, ccol = ss & 63;
            uint2 wv; wv.x = bf16x2_rne(sg[0], sg[1]); wv.y = bf16x2_rne(sg[2], sg[3]);
            *(uint2*)(pvT + ((((bb * 4 + kvv) * 32) + tl) * 32 + d) * 64 + ccol) = wv;
        }
    }
}

// ---------------- outproj GEMM: 64x128 tile, BK=64, gl_lds + XOR-8 swizzle -----
__global__ __launch_bounds__(256, 2) void outproj_gemm(
    const unsigned short* __restrict__ Ab, const unsigned short* __restrict__ Btb,
    float* __restrict__ out)
{
    __shared__ unsigned short As[64 * 64];    //  8 KB
    __shared__ unsigned short Bs[128 * 64];   // 16 KB
    const int tid = threadIdx.x, l = tid & 63, w = tid >> 6;
    const int l15 = l & 15, quad = l >> 4;
    const int m0 = blockIdx.x * 64, n0 = blockIdx.y * 128;
    const int wr = w & 1, wc = w >> 1;
    const int sr8 = l >> 3, sc8 = l & 7;
    f32x4 c[2][4];
    #pragma unroll
    for (int i = 0; i < 2; ++i)
        #pragma unroll
        for (int j = 0; j < 4; ++j) c[i][j] = (f32x4){0.f, 0.f, 0.f, 0.f};

    for (int k0 = 0; k0 < 512; k0 += 64) {
        #pragma unroll
        for (int j = 0; j < 2; ++j) {
            int R = w * 16 + j * 8, r = R + sr8;
            stage16(Ab + (m0 + r) * 512 + k0 + (sc8 ^ (r & 7)) * 8, &As[R * 64]);
        }
        #pragma unroll
        for (int j = 0; j < 4; ++j) {
            int R = j * 32 + w * 8, r = R + sr8;
            stage16(Btb + (n0 + r) * 512 + k0 + (sc8 ^ (r & 7)) * 8, &Bs[R * 64]);
        }
        __syncthreads();
        #pragma unroll
        for (int kh = 0; kh < 2; ++kh) {
            bshort8 a[2], b[4];
            #pragma unroll
            for (int ar = 0; ar < 2; ++ar) {
                int row = wr * 32 + ar * 16 + l15;
                a[ar] = *(const bshort8*)&As[row * 64 + (((kh * 4 + quad) ^ (row & 7)) * 8)];
            }
            #pragma unroll
            for (int bc = 0; bc < 4; ++bc) {
                int row = wc * 64 + bc * 16 + l15;
                b[bc] = *(const bshort8*)&Bs[row * 64 + (((kh * 4 + quad) ^ (row & 7)) * 8)];
            }
            #pragma unroll
            for (int ar = 0; ar < 2; ++ar)
                #pragma unroll
                for (int bc = 0; bc < 4; ++bc)
                    c[ar][bc] = __builtin_amdgcn_mfma_f32_16x16x32_bf16(a[ar], b[bc], c[ar][bc], 0, 0, 0);
        }
        __syncthreads();
    }

    #pragma unroll
    for (int ar = 0; ar < 2; ++ar)
        #pragma unroll
        for (int bc = 0; bc < 4; ++bc) {
            f32x4 v = c[ar][bc];
            const int col = n0 + wc * 64 + bc * 16 + l15;
            const int r0 = m0 + wr * 32 + ar * 16 + quad * 4;
            #pragma unroll
            for (int r = 0; r < 4; ++r)
                out[(r0 + r) * D_ + col] = v[r];
        }
}

// -------- Attention v10: paired q-tiles + 2-tile steps, private P slots --------
// Rounds 10/11 proved attn is chain-limited (~600cy QK->exp->pack->P->PV per
// 64-key pass), insensitive to schedule/occupancy. v10 processes TWO key
// tiles per barrier-iteration, each with its OWN P region (P[slot][wave]...),
// so up to 4 independent passes (B-t0, B-t1, A-t0, A-t1) coexist between
// barriers -> QK(t1) overlaps PV(t0) etc. Barrier count halves. Staging
// mechanics identical to the verified v8/v9 DMA path (2-tile pairs, dbuf).
#define PACK4(scv, KS, LS, PS) do {                                            \
    float p0_ = exp2f(scv[0]), p1_ = exp2f(scv[1]);                            \
    float p2_ = exp2f(scv[2]), p3_ = exp2f(scv[3]);                            \
    LS += p0_ + p1_ + p2_ + p3_;                                               \
    uint2 wv_; wv_.x = cvt_pk_bf16(p0_, p1_); wv_.y = cvt_pk_bf16(p2_, p3_);   \
    *(uint2*)&P[PS][wq][l15][(KS) * 16 + quad * 4] = wv_;                      \
} while (0)

#define DPACK4(scv, KS, LS, PS, QLANE, T0) do {                                \
    float p0_ = ((T0) + (KS) * 16 + quad * 4 + 0 <= (QLANE)) ? exp2f(scv[0]) : 0.f; \
    float p1_ = ((T0) + (KS) * 16 + quad * 4 + 1 <= (QLANE)) ? exp2f(scv[1]) : 0.f; \
    float p2_ = ((T0) + (KS) * 16 + quad * 4 + 2 <= (QLANE)) ? exp2f(scv[2]) : 0.f; \
    float p3_ = ((T0) + (KS) * 16 + quad * 4 + 3 <= (QLANE)) ? exp2f(scv[3]) : 0.f; \
    LS += p0_ + p1_ + p2_ + p3_;                                               \
    uint2 wv_; wv_.x = cvt_pk_bf16(p0_, p1_); wv_.y = cvt_pk_bf16(p2_, p3_);   \
    *(uint2*)&P[PS][wq][l15][(KS) * 16 + quad * 4] = wv_;                      \
} while (0)

#define TILEPASS(QF, A0, A1, LS, DG, QLANE, T0, TS) do {                       \
    f32x4 s0_, s1_, s2_, s3_;                                                  \
    {                                                                          \
        bshort8 kf0_, kf1_, kf2_, kf3_;                                        \
        if (quad < 2) {                                                        \
            kf0_ = *(const bshort8*)&Ks[cur][TS][0 * 256 + koff];              \
            kf1_ = *(const bshort8*)&Ks[cur][TS][1 * 256 + koff];              \
            kf2_ = *(const bshort8*)&Ks[cur][TS][2 * 256 + koff];              \
            kf3_ = *(const bshort8*)&Ks[cur][TS][3 * 256 + koff];              \
        } else if (quad == 2) { kf0_ = kone; kf1_ = kone; kf2_ = kone; kf3_ = kone; } \
        else                  { kf0_ = zero8; kf1_ = zero8; kf2_ = zero8; kf3_ = zero8; } \
        s0_ = __builtin_amdgcn_mfma_f32_16x16x32_bf16(kf0_, QF, zero4, 0, 0, 0); \
        s1_ = __builtin_amdgcn_mfma_f32_16x16x32_bf16(kf1_, QF, zero4, 0, 0, 0); \
        s2_ = __builtin_amdgcn_mfma_f32_16x16x32_bf16(kf2_, QF, zero4, 0, 0, 0); \
        s3_ = __builtin_amdgcn_mfma_f32_16x16x32_bf16(kf3_, QF, zero4, 0, 0, 0); \
    }                                                                          \
    if (!(DG)) {                                                               \
        PACK4(s0_, 0, LS, TS); PACK4(s1_, 1, LS, TS);                          \
        PACK4(s2_, 2, LS, TS); PACK4(s3_, 3, LS, TS);                          \
    } else {                                                                   \
        DPACK4(s0_, 0, LS, TS, QLANE, T0); DPACK4(s1_, 1, LS, TS, QLANE, T0);  \
        DPACK4(s2_, 2, LS, TS, QLANE, T0); DPACK4(s3_, 3, LS, TS, QLANE, T0);  \
    }                                                                          \
    {                                                                          \
        bshort8 pf0_ = *(const bshort8*)&P[TS][wq][l15][quad * 8];             \
        bshort8 pf1_ = *(const bshort8*)&P[TS][wq][l15][32 + quad * 8];        \
        bshort8 v0_ = *(const bshort8*)&Vs[cur][TS][vrow + vx0];               \
        bshort8 v1_ = *(const bshort8*)&Vs[cur][TS][vrow + vx1];               \
        bshort8 v2_ = *(const bshort8*)&Vs[cur][TS][vrow + 1024 + vx0];        \
        bshort8 v3_ = *(const bshort8*)&Vs[cur][TS][vrow + 1024 + vx1];        \
        A0 = __builtin_amdgcn_mfma_f32_16x16x32_bf16(v0_, pf0_, A0, 0, 0, 0);  \
        A1 = __builtin_amdgcn_mfma_f32_16x16x32_bf16(v2_, pf0_, A1, 0, 0, 0);  \
        A0 = __builtin_amdgcn_mfma_f32_16x16x32_bf16(v1_, pf1_, A0, 0, 0, 0);  \
        A1 = __builtin_amdgcn_mfma_f32_16x16x32_bf16(v3_, pf1_, A1, 0, 0, 0);  \
    }                                                                          \
} while (0)

#define WRITEOUT(QT, A0, A1, LS) do {                                          \
    float ls_ = LS;                                                            \
    ls_ += __shfl_xor(ls_, 16);                                                \
    ls_ += __shfl_xor(ls_, 32);                                                \
    const float inv_ = 1.f / ls_;                                              \
    const int tok_ = b * 2048 + (QT) * 64 + wq * 16 + l15;                     \
    float o0_[4], o1_[4];                                                      \
    _Pragma("unroll")                                                          \
    for (int r = 0; r < 4; ++r) {                                              \
        o0_[r] = e0v[r]     + dEv[r]     * (A0[r] * inv_);                     \
        o1_[r] = e0v[4 + r] + dEv[4 + r] * (A1[r] * inv_);                     \
    }                                                                          \
    uint2 w0_, w1_;                                                            \
    w0_.x = cvt_pk_bf16(o0_[0], o0_[1]); w0_.y = cvt_pk_bf16(o0_[2], o0_[3]);  \
    w1_.x = cvt_pk_bf16(o1_[0], o1_[1]); w1_.y = cvt_pk_bf16(o1_[2], o1_[3]);  \
    *(uint2*)(xo + tok_ * 512 + h * 32 + quad * 4)      = w0_;                 \
    *(uint2*)(xo + tok_ * 512 + h * 32 + 16 + quad * 4) = w1_;                 \
} while (0)

__global__ __launch_bounds__(256, 2) void attn_kernel(
    const unsigned short* __restrict__ qg_g, const unsigned short* __restrict__ pk_g,
    const unsigned short* __restrict__ pvT_g, const float* __restrict__ e0,
    const float* __restrict__ e1, unsigned short* __restrict__ xo)
{
    __shared__ unsigned short Ks[2][2][64 * 16]; //  8 KB [buf][slot][key][dim]
    __shared__ unsigned short Vs[2][2][32 * 64]; // 16 KB [buf][slot][vd][key] swz
    __shared__ unsigned short P[2][4][16][88];   // 22 KB [slot][wave][row][key]
    const int tid = threadIdx.x, l = tid & 63, wq = tid >> 6;
    const int l15 = l & 15, quad = l >> 4;
    const int g = blockIdx.x;
    const int bh = g & 31, p = g >> 5;        // p in 0..15
    const int qtA = p, qtB = 31 - p;          // qtB >= 16 always
    const int b = bh >> 4, h = bh & 15, kv = h >> 2;
    const unsigned short* pkb = pk_g + ((b * 4 + kv) * 2048) * 16;
    const unsigned short* pvb = pvT_g + (b * 4 + kv) * 65536;  // [tile][vd32][key64]
    const unsigned short* qgb = qg_g + ((b * 16 + h) * 2048) * 16;

    const f32x4 zero4 = {0.f, 0.f, 0.f, 0.f};
    const bshort8 zero8 = {0, 0, 0, 0, 0, 0, 0, 0};
    bshort8 kone = zero8; kone[0] = (short)0x3F80;   // bf16 1.0 (k=16 slot)

    // q fragments for both tiles (32 B rows; select by quad)
    bshort8 qfragA = zero8, qfragB = zero8;
    {
        const unsigned short* qrow = qgb + (qtA * 64 + wq * 16 + l15) * 16;
        uint4 qu0 = *(const uint4*)qrow;
        uint4 qu1 = *(const uint4*)(qrow + 8);
        float s = sum2bf(qu0.x) + sum2bf(qu0.y) + sum2bf(qu0.z) + sum2bf(qu0.w)
                + sum2bf(qu1.x) + sum2bf(qu1.y) + sum2bf(qu1.z) + sum2bf(qu1.w);
        if (quad == 0)      qfragA = __builtin_bit_cast(bshort8, qu0);
        else if (quad == 1) qfragA = __builtin_bit_cast(bshort8, qu1);
        else if (quad == 2) qfragA[0] = (short)bf16_rne(-8.f * L2E_ - 0.5f * s);
    }
    {
        const unsigned short* qrow = qgb + (qtB * 64 + wq * 16 + l15) * 16;
        uint4 qu0 = *(const uint4*)qrow;
        uint4 qu1 = *(const uint4*)(qrow + 8);
        float s = sum2bf(qu0.x) + sum2bf(qu0.y) + sum2bf(qu0.z) + sum2bf(qu0.w)
                + sum2bf(qu1.x) + sum2bf(qu1.y) + sum2bf(qu1.z) + sum2bf(qu1.w);
        if (quad == 0)      qfragB = __builtin_bit_cast(bshort8, qu0);
        else if (quad == 1) qfragB = __builtin_bit_cast(bshort8, qu1);
        else if (quad == 2) qfragB[0] = (short)bf16_rne(-8.f * L2E_ - 0.5f * s);
    }

    f32x4 accA0 = zero4, accA1 = zero4, accB0 = zero4, accB1 = zero4;
    float lsumA = 0.f, lsumB = 0.f;

    // --- staging pointers (per-thread constants) ---
    // V: full 256-thread cooperative fill per tile slot (4 KB each).
    const int vrow_s = tid >> 3;
    const unsigned short* vsrc = pvb + vrow_s * 64 + (((tid & 7) ^ (vrow_s & 7)) * 8);
    // K: 128 threads per tile slot (2 KB each); slot = tid>>7.
    const int ktid = tid & 127, kslot = tid >> 7;
    const unsigned short* ksrc = pkb + (ktid >> 1) * 16 + (ktid & 1) * 8;

    // --- fragment read offsets (shorts) ---
    const int koff = l15 * 16 + quad * 8;
    const int vx0 = ((quad ^ (l15 & 7)) * 8);
    const int vx1 = (((quad + 4) ^ (l15 & 7)) * 8);
    const int vrow = l15 * 64;

    const int qlaneA = qtA * 64 + wq * 16 + l15;
    const int qlaneB = qtB * 64 + wq * 16 + l15;

    // prologue: stage tiles 0,1 into buf 0 (qtB >= 16, so both always valid)
    stage16(vsrc, &Vs[0][0][tid * 8]);
    stage16(vsrc + 2048, &Vs[0][1][tid * 8]);
    stage16(ksrc + kslot * 1024, &Ks[0][kslot][ktid * 8]);
    __syncthreads();

    int cur = 0;
    for (int tt = 0; tt <= qtB; tt += 2) {
        // ---- prefetch pair (tt+2, tt+3) into the idle buffer ----
        if (tt + 2 <= qtB) {
            const int ns = cur ^ 1;
            const int n1 = (tt + 3 <= qtB) ? tt + 3 : qtB;
            stage16(vsrc + (tt + 2) * 2048, &Vs[ns][0][tid * 8]);
            stage16(vsrc + n1 * 2048, &Vs[ns][1][tid * 8]);
            const int kt = (tt + 2 + kslot <= qtB) ? tt + 2 + kslot : qtB;
            stage16(ksrc + kt * 1024, &Ks[ns][kslot][ktid * 8]);
        }
        const int t0 = tt, t1 = tt + 1;
        // B passes (t0 always <= qtB)
        TILEPASS(qfragB, accB0, accB1, lsumB, t0 == qtB, qlaneB, t0 * 64, 0);
        if (t1 <= qtB)
            TILEPASS(qfragB, accB0, accB1, lsumB, t1 == qtB, qlaneB, t1 * 64, 1);
        // A passes (active while t <= qtA)
        if (t0 <= qtA)
            TILEPASS(qfragA, accA0, accA1, lsumA, t0 == qtA, qlaneA, t0 * 64, 0);
        if (t1 <= qtA)
            TILEPASS(qfragA, accA0, accA1, lsumA, t1 == qtA, qlaneA, t1 * 64, 1);
        // one barrier per 2 staged tiles: drains this iter's DMA so the idle
        // buffer is ready, and orders all waves' reads before overwrite.
        __syncthreads();
        cur ^= 1;
    }

    float e0v[8], dEv[8];
    #pragma unroll
    for (int vs = 0; vs < 2; ++vs)
        #pragma unroll
        for (int r = 0; r < 4; ++r) {
            int idx2 = h * 32 + vs * 16 + quad * 4 + r;
            float a = e0[idx2];
            e0v[vs * 4 + r] = a; dEv[vs * 4 + r] = e1[idx2] - a;
        }
    WRITEOUT(qtA, accA0, accA1, lsumA);
    WRITEOUT(qtB, accB0, accB1, lsumB);
}

extern "C" void kernel_launch(void* const* d_in, const int* in_sizes, int n_in,
                              void* d_out, int out_size, void* d_ws, size_t ws_size,
                              hipStream_t stream)
{
    const float* hs = (const float*)d_in[0];
    const float* Wq = (const float*)d_in[1];
    const float* Wk = (const float*)d_in[2];
    const float* Wv = (const float*)d_in[3];
    const float* Wo = (const float*)d_in[4];
    const float* e0 = (const float*)d_in[5];
    const float* e1 = (const float*)d_in[6];
    float* out = (float*)d_out;

    char* ws = (char*)d_ws;
    unsigned short* hs_b   = (unsigned short*)(ws);
    unsigned short* xo     = (unsigned short*)(ws);
    unsigned short* Wcat_t = (unsigned short*)(ws + 8388608);
    unsigned short* Wot    = (unsigned short*)(ws + 8388608 + 917504);
    unsigned short* qg     = (unsigned short*)(ws + 10354688);
    unsigned short* pk     = (unsigned short*)(ws + 12451840);
    unsigned short* pvT    = (unsigned short*)(ws + 12976128);

    prep_kernel<<<2288, 256, 0, stream>>>(hs, Wq, Wk, Wv, Wo, hs_b, Wcat_t, Wot);
    proj_gemm<<<dim3(64, 7), 256, 0, stream>>>(hs_b, Wcat_t, qg, pk, pvT);
    attn_kernel<<<512, 256, 0, stream>>>(qg, pk, pvT, e0, e1, xo);
    outproj_gemm<<<dim3(64, 8), 256, 0, stream>>>(xo, Wot, out);
}

// Round 14
// 128.583 us; speedup vs baseline: 1.0549x; 1.0549x over previous
//
#include <hip/hip_runtime.h>
#include <hip/hip_bf16.h>

#define B_    2
#define S_    2048
#define D_    1024
#define H_    16
#define KV_   4
#define QKB_  16
#define VB_   32
#define NTOK  (B_ * S_)   // 4096
#define L2E_  1.44269504088896f

typedef __attribute__((ext_vector_type(8))) short bshort8;
typedef __attribute__((ext_vector_type(4))) float f32x4;

__device__ __forceinline__ unsigned short bf16_rne(float x) {
    unsigned u = __float_as_uint(x);
    return (unsigned short)((u + 0x7FFFu + ((u >> 16) & 1u)) >> 16);
}
__device__ __forceinline__ unsigned bf16x2_rne(float lo, float hi) {
    return (unsigned)bf16_rne(lo) | ((unsigned)bf16_rne(hi) << 16);
}
__device__ __forceinline__ unsigned cvt_pk_bf16(float lo, float hi) {
    unsigned r;
    asm("v_cvt_pk_bf16_f32 %0, %1, %2" : "=v"(r) : "v"(lo), "v"(hi));
    return r;
}
__device__ __forceinline__ float sum2bf(unsigned u) {
    return __uint_as_float(u << 16) + __uint_as_float(u & 0xFFFF0000u);
}
__device__ __forceinline__ void stage16(const unsigned short* g, unsigned short* l) {
    __builtin_amdgcn_global_load_lds(
        (const __attribute__((address_space(1))) void*)g,
        (__attribute__((address_space(3))) void*)l, 16, 0, 0);
}

// Raw HW exp2. Attn args are in [-24, 0] where ocml's range-fixup is a no-op,
// so this is bit-identical to exp2f there -- minus ~4 VALU ops per call.
#if defined(__has_builtin)
#if __has_builtin(__builtin_amdgcn_exp2f)
#define EXPF(x) __builtin_amdgcn_exp2f(x)
#endif
#endif
#ifndef EXPF
__device__ __forceinline__ float expf_hw_(float x) {
    float r;
    asm volatile("v_exp_f32 %0, %1\n\ts_nop 1" : "=v"(r) : "v"(x));
    return r;
}
#define EXPF(x) expf_hw_(x)
#endif

// ---------------- Prep: hs->bf16 (blocks 0..2047) + weight transpose (2048..2287) --
__global__ __launch_bounds__(256) void prep_kernel(
    const float* __restrict__ hs,
    const float* __restrict__ Wq, const float* __restrict__ Wk,
    const float* __restrict__ Wv, const float* __restrict__ Wo,
    unsigned short* __restrict__ hs_b,
    unsigned short* __restrict__ Wcat_t, unsigned short* __restrict__ Wot)
{
    __shared__ float T[64][65];
    const int t = threadIdx.x;
    if (blockIdx.x < 2048) {
        int i = blockIdx.x * 256 + t;
        const float4* s = (const float4*)hs;
        float4 a = s[2 * i], b = s[2 * i + 1];
        uint4 o;
        o.x = bf16x2_rne(a.x, a.y); o.y = bf16x2_rne(a.z, a.w);
        o.z = bf16x2_rne(b.x, b.y); o.w = bf16x2_rne(b.z, b.w);
        ((uint4*)hs_b)[i] = o;
        return;
    }
    const int bid = blockIdx.x - 2048;
    const float* src; unsigned short* dst; int K, N, tk, tn, drow0;
    if (bid < 64)       { src = Wq; dst = Wcat_t; K = 1024; N = 256;  int r = bid;       tk = r & 15; tn = r >> 4; drow0 = 0; }
    else if (bid < 80)  { src = Wk; dst = Wcat_t; K = 1024; N = 64;   int r = bid - 64;  tk = r;      tn = 0;      drow0 = 256; }
    else if (bid < 112) { src = Wv; dst = Wcat_t; K = 1024; N = 128;  int r = bid - 80;  tk = r & 15; tn = r >> 4; drow0 = 320; }
    else                { src = Wo; dst = Wot;    K = 512;  N = 1024; int r = bid - 112; tk = r & 7;  tn = r >> 3; drow0 = 0; }
    const int k0 = tk * 64, n0 = tn * 64;
    const int rr = t >> 4, cc = (t & 15) * 4;
    #pragma unroll
    for (int i = 0; i < 4; ++i) {
        float4 v = *(const float4*)(src + (k0 + rr + i * 16) * N + n0 + cc);
        T[rr + i * 16][cc + 0] = v.x; T[rr + i * 16][cc + 1] = v.y;
        T[rr + i * 16][cc + 2] = v.z; T[rr + i * 16][cc + 3] = v.w;
    }
    __syncthreads();
    const int nloc = t >> 2, kc = (t & 3) * 16;
    unsigned o[8];
    #pragma unroll
    for (int j = 0; j < 8; ++j)
        o[j] = bf16x2_rne(T[kc + 2 * j][nloc], T[kc + 2 * j + 1][nloc]);
    unsigned short* dp = dst + (drow0 + n0 + nloc) * K + k0 + kc;
    uint4 w0; w0.x = o[0]; w0.y = o[1]; w0.z = o[2]; w0.w = o[3];
    uint4 w1; w1.x = o[4]; w1.y = o[5]; w1.z = o[6]; w1.w = o[7];
    *(uint4*)(dp) = w0;
    *(uint4*)(dp + 8) = w1;
}

// ---------------- proj GEMM: 64x64 tile, BK=64, gl_lds + XOR-8 swizzle ---------
__global__ __launch_bounds__(256, 4) void proj_gemm(
    const unsigned short* __restrict__ Ab, const unsigned short* __restrict__ Btb,
    unsigned short* __restrict__ qg, unsigned short* __restrict__ pko,
    unsigned short* __restrict__ pvT)
{
    __shared__ unsigned short As[64 * 64];    // 8 KB
    __shared__ unsigned short Bs[64 * 64];    // 8 KB
    const int tid = threadIdx.x, l = tid & 63, w = tid >> 6;
    const int l15 = l & 15, quad = l >> 4;
    const int m0 = blockIdx.x * 64, n0 = blockIdx.y * 64;
    const int sr8 = l >> 3, sc8 = l & 7;
    f32x4 c[4];
    #pragma unroll
    for (int j = 0; j < 4; ++j) c[j] = (f32x4){0.f, 0.f, 0.f, 0.f};

    for (int k0 = 0; k0 < 1024; k0 += 64) {
        int R0 = w * 8, r0 = R0 + sr8;
        int R1 = 32 + w * 8, r1 = R1 + sr8;
        stage16(Ab  + (m0 + r0) * 1024 + k0 + (sc8 ^ (r0 & 7)) * 8, &As[R0 * 64]);
        stage16(Ab  + (m0 + r1) * 1024 + k0 + (sc8 ^ (r1 & 7)) * 8, &As[R1 * 64]);
        stage16(Btb + (n0 + r0) * 1024 + k0 + (sc8 ^ (r0 & 7)) * 8, &Bs[R0 * 64]);
        stage16(Btb + (n0 + r1) * 1024 + k0 + (sc8 ^ (r1 & 7)) * 8, &Bs[R1 * 64]);
        __syncthreads();
        #pragma unroll
        for (int kh = 0; kh < 2; ++kh) {
            const int arow = w * 16 + l15;
            bshort8 a = *(const bshort8*)&As[arow * 64 + (((kh * 4 + quad) ^ (arow & 7)) * 8)];
            #pragma unroll
            for (int bc = 0; bc < 4; ++bc) {
                const int brow = bc * 16 + l15;
                bshort8 b = *(const bshort8*)&Bs[brow * 64 + (((kh * 4 + quad) ^ (brow & 7)) * 8)];
                c[bc] = __builtin_amdgcn_mfma_f32_16x16x32_bf16(a, b, c[bc], 0, 0, 0);
            }
        }
        __syncthreads();
    }

    const int tok0 = m0 + w * 16 + quad * 4;
    #pragma unroll
    for (int bc = 0; bc < 4; ++bc) {
        f32x4 v = c[bc];
        const int n = n0 + bc * 16 + l15;
        float sg[4];
        #pragma unroll
        for (int r = 0; r < 4; ++r)
            sg[r] = 1.f / (1.f + exp2f(-v[r] * L2E_));
        if (n < 256) {
            const int hh = n >> 4, d = n & 15;
            #pragma unroll
            for (int r = 0; r < 4; ++r) {
                int tok = tok0 + r, bb = tok >> 11, ss = tok & 2047;
                qg[(((bb * 16 + hh) * 2048) + ss) * 16 + d] =
                    bf16_rne(L2E_ * (2.f * sg[r] - 1.f));
            }
        } else if (n < 320) {
            const int j = n - 256, kvv = j >> 4, d = j & 15;
            #pragma unroll
            for (int r = 0; r < 4; ++r) {
                int tok = tok0 + r, bb = tok >> 11, ss = tok & 2047;
                pko[(((bb * 4 + kvv) * 2048) + ss) * 16 + d] = bf16_rne(sg[r]);
            }
        } else {
            const int j = n - 320, kvv = j >> 5, d = j & 31;
            const int bb = tok0 >> 11, ss = tok0 & 2047;
            const int tl = ss >> 6, ccol = ss & 63;
            uint2 wv; wv.x = bf16x2_rne(sg[0], sg[1]); wv.y = bf16x2_rne(sg[2], sg[3]);
            *(uint2*)(pvT + ((((bb * 4 + kvv) * 32) + tl) * 32 + d) * 64 + ccol) = wv;
        }
    }
}

// ---------------- outproj GEMM: 64x128 tile, BK=64, gl_lds + XOR-8 swizzle -----
__global__ __launch_bounds__(256, 2) void outproj_gemm(
    const unsigned short* __restrict__ Ab, const unsigned short* __restrict__ Btb,
    float* __restrict__ out)
{
    __shared__ unsigned short As[64 * 64];    //  8 KB
    __shared__ unsigned short Bs[128 * 64];   // 16 KB
    const int tid = threadIdx.x, l = tid & 63, w = tid >> 6;
    const int l15 = l & 15, quad = l >> 4;
    const int m0 = blockIdx.x * 64, n0 = blockIdx.y * 128;
    const int wr = w & 1, wc = w >> 1;
    const int sr8 = l >> 3, sc8 = l & 7;
    f32x4 c[2][4];
    #pragma unroll
    for (int i = 0; i < 2; ++i)
        #pragma unroll
        for (int j = 0; j < 4; ++j) c[i][j] = (f32x4){0.f, 0.f, 0.f, 0.f};

    for (int k0 = 0; k0 < 512; k0 += 64) {
        #pragma unroll
        for (int j = 0; j < 2; ++j) {
            int R = w * 16 + j * 8, r = R + sr8;
            stage16(Ab + (m0 + r) * 512 + k0 + (sc8 ^ (r & 7)) * 8, &As[R * 64]);
        }
        #pragma unroll
        for (int j = 0; j < 4; ++j) {
            int R = j * 32 + w * 8, r = R + sr8;
            stage16(Btb + (n0 + r) * 512 + k0 + (sc8 ^ (r & 7)) * 8, &Bs[R * 64]);
        }
        __syncthreads();
        #pragma unroll
        for (int kh = 0; kh < 2; ++kh) {
            bshort8 a[2], b[4];
            #pragma unroll
            for (int ar = 0; ar < 2; ++ar) {
                int row = wr * 32 + ar * 16 + l15;
                a[ar] = *(const bshort8*)&As[row * 64 + (((kh * 4 + quad) ^ (row & 7)) * 8)];
            }
            #pragma unroll
            for (int bc = 0; bc < 4; ++bc) {
                int row = wc * 64 + bc * 16 + l15;
                b[bc] = *(const bshort8*)&Bs[row * 64 + (((kh * 4 + quad) ^ (row & 7)) * 8)];
            }
            #pragma unroll
            for (int ar = 0; ar < 2; ++ar)
                #pragma unroll
                for (int bc = 0; bc < 4; ++bc)
                    c[ar][bc] = __builtin_amdgcn_mfma_f32_16x16x32_bf16(a[ar], b[bc], c[ar][bc], 0, 0, 0);
        }
        __syncthreads();
    }

    #pragma unroll
    for (int ar = 0; ar < 2; ++ar)
        #pragma unroll
        for (int bc = 0; bc < 4; ++bc) {
            f32x4 v = c[ar][bc];
            const int col = n0 + wc * 64 + bc * 16 + l15;
            const int r0 = m0 + wr * 32 + ar * 16 + quad * 4;
            #pragma unroll
            for (int r = 0; r < 4; ++r)
                out[(r0 + r) * D_ + col] = v[r];
        }
}

// -------- Attention v11: round-10 v8 body + raw v_exp_f32 + split lsum chain ---
// Rounds 10-12 showed attn invariant to occupancy/barriers/ILP structure ->
// the binding resource is the per-pass VALU/trans issue stream. Dominant item:
// 16x exp2f/pass, each lowered by ocml to ~5 ops (range fixup + quarter-rate
// v_exp). Attn args are in [-24,0] where the fixup is a no-op -> EXPF uses the
// raw HW instruction (bit-identical here), cutting ~130 issue-cycles/pass.
// lsum also split into two independent partials (shorter serial accumulate).
// All other mechanics identical to the verified round-10 kernel.
__global__ __launch_bounds__(256, 4) void attn_kernel(
    const unsigned short* __restrict__ qg_g, const unsigned short* __restrict__ pk_g,
    const unsigned short* __restrict__ pvT_g, const float* __restrict__ e0,
    const float* __restrict__ e1, unsigned short* __restrict__ xo)
{
    __shared__ unsigned short Ks[2][64 * 16]; //  4 KB [buf][key][dim], linear
    __shared__ unsigned short Vs[2][32 * 64]; //  8 KB [buf][vd][key], XOR-8 granule swizzle
    __shared__ unsigned short P[4][16][88];   // 11 KB
    const int tid = threadIdx.x, l = tid & 63, wq = tid >> 6;
    const int l15 = l & 15, quad = l >> 4;
    // balanced mapping: CU's 4 resident blocks (g, g+256, g+512, g+768) get
    // qt {r, 31-r, 8+r, 23-r} -> 66 tile-iters per CU, uniform.
    const int g = blockIdx.x;
    const int idx = g & 255, kg = g >> 8;
    const int bh = idx & 31, rr = idx >> 5;
    int qt;
    if      (kg == 0) qt = rr;
    else if (kg == 1) qt = 31 - rr;
    else if (kg == 2) qt = 8 + rr;
    else              qt = 23 - rr;
    const int b = bh >> 4, h = bh & 15, kv = h >> 2;
    const int qbase = qt * 64;
    const unsigned short* pkb = pk_g + ((b * 4 + kv) * 2048) * 16;
    const unsigned short* pvb = pvT_g + (b * 4 + kv) * 65536;  // [tile][vd32][key64]
    const unsigned short* qgb = qg_g + ((b * 16 + h) * 2048) * 16;

    const f32x4 zero4 = {0.f, 0.f, 0.f, 0.f};
    const bshort8 zero8 = {0, 0, 0, 0, 0, 0, 0, 0};

    // q row straight from global: 32 B; fragment select by quad.
    const unsigned short* qrow = qgb + (qbase + wq * 16 + l15) * 16;
    uint4 qu0 = *(const uint4*)qrow;
    uint4 qu1 = *(const uint4*)(qrow + 8);
    float s = sum2bf(qu0.x) + sum2bf(qu0.y) + sum2bf(qu0.z) + sum2bf(qu0.w)
            + sum2bf(qu1.x) + sum2bf(qu1.y) + sum2bf(qu1.z) + sum2bf(qu1.w);
    bshort8 qfrag = zero8;
    if (quad == 0)      qfrag = __builtin_bit_cast(bshort8, qu0);
    else if (quad == 1) qfrag = __builtin_bit_cast(bshort8, qu1);
    else if (quad == 2) qfrag[0] = (short)bf16_rne(-8.f * L2E_ - 0.5f * s);

    bshort8 kone = zero8; kone[0] = (short)0x3F80;   // bf16 1.0 (k=16 slot)

    f32x4 acc0 = zero4, acc1 = zero4;
    float lsum0 = 0.f, lsum1 = 0.f;

    // --- staging pointers (per-thread constants) ---
    const int vrow_s = tid >> 3;
    const unsigned short* vsrc = pvb + vrow_s * 64 + (((tid & 7) ^ (vrow_s & 7)) * 8);
    const unsigned short* ksrc = pkb + (tid >> 1) * 16 + (tid & 1) * 8;

    // --- fragment read offsets (shorts) ---
    const int koff = l15 * 16 + quad * 8;                 // K: [key=ks*16+l15][dim half=quad]
    const int vx0 = ((quad ^ (l15 & 7)) * 8);             // V granule quad   (swizzled)
    const int vx1 = (((quad + 4) ^ (l15 & 7)) * 8);       // V granule quad+4 (swizzled)
    const int vrow = l15 * 64;

    const int q_lane = qbase + wq * 16 + l15;

    // prologue: stage tile 0 into buf 0
    stage16(vsrc, &Vs[0][tid * 8]);
    if (tid < 128) stage16(ksrc, &Ks[0][tid * 8]);
    __syncthreads();

    int cur = 0;
    for (int t = 0; t <= qt; ++t) {
        // ---- prefetch tile t+1 into the idle buffer (async DMA, no wait) ----
        if (t < qt) {
            stage16(vsrc + (t + 1) * 2048, &Vs[cur ^ 1][tid * 8]);
            if (tid < 128) stage16(ksrc + (t + 1) * 1024, &Ks[cur ^ 1][tid * 8]);
        }

        // ---- QK^T from buf[cur] ----
        f32x4 sc[4];
        #pragma unroll
        for (int ks = 0; ks < 4; ++ks) {
            bshort8 kf;
            if (quad < 2)       kf = *(const bshort8*)&Ks[cur][ks * 256 + koff];
            else if (quad == 2) kf = kone;
            else                kf = zero8;
            sc[ks] = __builtin_amdgcn_mfma_f32_16x16x32_bf16(kf, qfrag, zero4, 0, 0, 0);
        }
        // ---- exp + pack into P (raw HW exp2; args in [-24,0]) ----
        if (t < qt) {
            #pragma unroll
            for (int ks = 0; ks < 4; ++ks) {
                float p0 = EXPF(sc[ks][0]), p1 = EXPF(sc[ks][1]);
                float p2 = EXPF(sc[ks][2]), p3 = EXPF(sc[ks][3]);
                if (ks & 1) lsum1 += (p0 + p1) + (p2 + p3);
                else        lsum0 += (p0 + p1) + (p2 + p3);
                uint2 wv; wv.x = cvt_pk_bf16(p0, p1); wv.y = cvt_pk_bf16(p2, p3);
                *(uint2*)&P[wq][l15][ks * 16 + quad * 4] = wv;
            }
        } else {   // diagonal tile: causal mask
            const int t0 = qt * 64;
            #pragma unroll
            for (int ks = 0; ks < 4; ++ks) {
                float pv0[4];
                #pragma unroll
                for (int r = 0; r < 4; ++r) {
                    const int tg = t0 + ks * 16 + quad * 4 + r;
                    float pp = (tg <= q_lane) ? EXPF(sc[ks][r]) : 0.f;
                    pv0[r] = pp;
                }
                if (ks & 1) lsum1 += (pv0[0] + pv0[1]) + (pv0[2] + pv0[3]);
                else        lsum0 += (pv0[0] + pv0[1]) + (pv0[2] + pv0[3]);
                uint2 wv; wv.x = cvt_pk_bf16(pv0[0], pv0[1]); wv.y = cvt_pk_bf16(pv0[2], pv0[3]);
                *(uint2*)&P[wq][l15][ks * 16 + quad * 4] = wv;
            }
        }
        // ---- PV from buf[cur] ----
        {
            bshort8 pf0 = *(const bshort8*)&P[wq][l15][quad * 8];
            bshort8 pf1 = *(const bshort8*)&P[wq][l15][32 + quad * 8];
            bshort8 v0 = *(const bshort8*)&Vs[cur][vrow + vx0];
            bshort8 v1 = *(const bshort8*)&Vs[cur][vrow + vx1];
            bshort8 v2 = *(const bshort8*)&Vs[cur][vrow + 1024 + vx0];
            bshort8 v3 = *(const bshort8*)&Vs[cur][vrow + 1024 + vx1];
            acc0 = __builtin_amdgcn_mfma_f32_16x16x32_bf16(v0, pf0, acc0, 0, 0, 0);
            acc1 = __builtin_amdgcn_mfma_f32_16x16x32_bf16(v2, pf0, acc1, 0, 0, 0);
            acc0 = __builtin_amdgcn_mfma_f32_16x16x32_bf16(v1, pf1, acc0, 0, 0, 0);
            acc1 = __builtin_amdgcn_mfma_f32_16x16x32_bf16(v3, pf1, acc1, 0, 0, 0);
        }
        // one barrier per tile: drains this iter's DMA so buf[cur^1] is ready,
        // and orders all waves' reads of buf[cur] before the next overwrite.
        __syncthreads();
        cur ^= 1;
    }

    float lsum = lsum0 + lsum1;
    lsum += __shfl_xor(lsum, 16);
    lsum += __shfl_xor(lsum, 32);
    const float inv = 1.f / lsum;

    float e0v[8], dEv[8];
    #pragma unroll
    for (int vs = 0; vs < 2; ++vs)
        #pragma unroll
        for (int r = 0; r < 4; ++r) {
            int idx2 = h * 32 + vs * 16 + quad * 4 + r;
            float a = e0[idx2];
            e0v[vs * 4 + r] = a; dEv[vs * 4 + r] = e1[idx2] - a;
        }
    const int tok = b * 2048 + qbase + wq * 16 + l15;
    float o0[4], o1[4];
    #pragma unroll
    for (int r = 0; r < 4; ++r) {
        o0[r] = e0v[r]     + dEv[r]     * (acc0[r] * inv);
        o1[r] = e0v[4 + r] + dEv[4 + r] * (acc1[r] * inv);
    }
    uint2 w0; w0.x = cvt_pk_bf16(o0[0], o0[1]); w0.y = cvt_pk_bf16(o0[2], o0[3]);
    uint2 w1; w1.x = cvt_pk_bf16(o1[0], o1[1]); w1.y = cvt_pk_bf16(o1[2], o1[3]);
    *(uint2*)(xo + tok * 512 + h * 32 + quad * 4)      = w0;
    *(uint2*)(xo + tok * 512 + h * 32 + 16 + quad * 4) = w1;
}

extern "C" void kernel_launch(void* const* d_in, const int* in_sizes, int n_in,
                              void* d_out, int out_size, void* d_ws, size_t ws_size,
                              hipStream_t stream)
{
    const float* hs = (const float*)d_in[0];
    const float* Wq = (const float*)d_in[1];
    const float* Wk = (const float*)d_in[2];
    const float* Wv = (const float*)d_in[3];
    const float* Wo = (const float*)d_in[4];
    const float* e0 = (const float*)d_in[5];
    const float* e1 = (const float*)d_in[6];
    float* out = (float*)d_out;

    char* ws = (char*)d_ws;
    unsigned short* hs_b   = (unsigned short*)(ws);
    unsigned short* xo     = (unsigned short*)(ws);
    unsigned short* Wcat_t = (unsigned short*)(ws + 8388608);
    unsigned short* Wot    = (unsigned short*)(ws + 8388608 + 917504);
    unsigned short* qg     = (unsigned short*)(ws + 10354688);
    unsigned short* pk     = (unsigned short*)(ws + 12451840);
    unsigned short* pvT    = (unsigned short*)(ws + 12976128);

    prep_kernel<<<2288, 256, 0, stream>>>(hs, Wq, Wk, Wv, Wo, hs_b, Wcat_t, Wot);
    proj_gemm<<<dim3(64, 7), 256, 0, stream>>>(hs_b, Wcat_t, qg, pk, pvT);
    attn_kernel<<<1024, 256, 0, stream>>>(qg, pk, pvT, e0, e1, xo);
    outproj_gemm<<<dim3(64, 8), 256, 0, stream>>>(xo, Wot, out);
}